// Round 10
// baseline (99.214 us; speedup 1.0000x reference)
//
#include <hip/hip_runtime.h>
#include <hip/hip_bf16.h>

#define B_   2
#define T_   2048
#define D_   1024
#define NH_  16
#define NKV_ 4
#define HD_  64
#define E_   1536  // (NH + 2*NKV) * HD
#define LOG2E 1.4426950408889634f

typedef __attribute__((ext_vector_type(8))) __bf16 bf16x8;
typedef __attribute__((ext_vector_type(4))) __bf16 bf16x4;
typedef __attribute__((ext_vector_type(4))) float f32x4;

// async global->LDS, 16B per lane. LDS dest = wave-uniform base + lane*16.
static __device__ __forceinline__ void gld_lds16(const unsigned short* g, unsigned short* l) {
  __builtin_amdgcn_global_load_lds(
      (const __attribute__((address_space(1))) unsigned int*)(unsigned long long)(const void*)g,
      (__attribute__((address_space(3))) unsigned int*)(unsigned int)(unsigned long long)(void*)l,
      16, 0, 0);
}

// raw hardware ops (avoid OCML guard sequences; args bounded, FTZ exact for us)
static __device__ __forceinline__ float fexp2(float x) {
  float r; asm("v_exp_f32 %0, %1" : "=v"(r) : "v"(x)); return r;
}
static __device__ __forceinline__ float fmax3(float a, float b, float c) {
  float r; asm("v_max3_f32 %0, %1, %2, %3" : "=v"(r) : "v"(a), "v"(b), "v"(c)); return r;
}
static __device__ __forceinline__ float frcp(float x) {
  float r; asm("v_rcp_f32 %0, %1" : "=v"(r) : "v"(x)); return r;
}

// counted-vmcnt barrier: loads stay in flight across the barrier (T3/T4, m201 pattern)
#define PIPE_BARRIER(N) {                                   \
  asm volatile("s_waitcnt vmcnt(" #N ")" ::: "memory");     \
  __builtin_amdgcn_s_barrier();                             \
  __builtin_amdgcn_sched_barrier(0); }

#define CVT8(dst, f0, f1) {                                                    \
  dst[0] = (__bf16)f0.x; dst[1] = (__bf16)f0.y;                               \
  dst[2] = (__bf16)f0.z; dst[3] = (__bf16)f0.w;                               \
  dst[4] = (__bf16)f1.x; dst[5] = (__bf16)f1.y;                               \
  dst[6] = (__bf16)f1.z; dst[7] = (__bf16)f1.w; }

// ---- fp32->bf16 convert, PRE-SWIZZLED: buf[n][c ^ 8*(n&7)] = src[n][c] ----
__global__ void k_convert_all(const float* __restrict__ x, const float* __restrict__ wq,
                              const float* __restrict__ wp,
                              unsigned short* __restrict__ xb, unsigned short* __restrict__ wqb,
                              unsigned short* __restrict__ wpb) {
  int i = blockIdx.x * blockDim.x + threadIdx.x;  // 851968 total groups of 8
  const float* src; unsigned short* dst; int j;
  if (i < 524288)      { src = x;  dst = xb;  j = i; }
  else if (i < 720896) { src = wq; dst = wqb; j = i - 524288; }
  else                 { src = wp; dst = wpb; j = i - 720896; }
  int n = j >> 7, c8 = (j & 127) * 8;
  const float4* p = (const float4*)(src + (size_t)n * 1024 + c8);
  float4 a = p[0], b = p[1];
  bf16x8 o; CVT8(o, a, b);
  *(bf16x8*)(dst + (size_t)n * 1024 + (c8 ^ ((n & 7) * 8))) = o;
}

// ---------------- QKV GEMM: pre-swizzled bf16 A and W via gld_lds, fused epilogue ------------
// tile 128Mx64N, BK=64, 3-deep pipeline with counted vmcnt. grid (24, 32) = 768 blocks.
__global__ __launch_bounds__(256) void k_gemm_qkv(
    const unsigned short* __restrict__ A,   // pre-swizzled bf16 x
    const unsigned short* __restrict__ W,   // pre-swizzled bf16
    const float* __restrict__ cosT, const float* __restrict__ sinT,
    const float* __restrict__ v0,
    const float* __restrict__ vrl, const float* __restrict__ qks,
    unsigned short* __restrict__ qb, unsigned short* __restrict__ kb,
    unsigned short* __restrict__ vb) {
  __shared__ __align__(16) unsigned short As[3][128 * 64];
  __shared__ __align__(16) unsigned short Ws[3][64 * 64];
  int tid = threadIdx.x;
  int w = tid >> 6, l = tid & 63, lo = l & 15, hi = l >> 4;
  int f = blockIdx.y * 24 + blockIdx.x;           // 768 blocks, %8==0
  int f2 = (f & 7) * 96 + (f >> 3);               // XCD swizzle
  int bn = f2 % 24, bm = f2 / 24;
  int rsw = (lo & 7) * 8;                         // read-side swizzle

  const unsigned short* Ab = A + (size_t)bm * 128 * 1024;
  const unsigned short* Wb = W + (size_t)bn * 64 * 1024;

  f32x4 acc[2][4];
#pragma unroll
  for (int mi = 0; mi < 2; ++mi)
#pragma unroll
    for (int ni = 0; ni < 4; ++ni) acc[mi][ni] = (f32x4){0.f, 0.f, 0.f, 0.f};

#define STAGE(kt, buf) {                                                       \
  int k0 = (kt) * 64;                                                         \
  _Pragma("unroll") for (int ii = 0; ii < 4; ++ii) {                          \
    int sb = ii * 256 + w * 64;                                               \
    gld_lds16(Ab + (size_t)((sb + l) >> 3) * 1024 + k0 + ((sb + l) & 7) * 8,  \
              &As[buf][sb * 8]); }                                            \
  _Pragma("unroll") for (int ii = 0; ii < 2; ++ii) {                          \
    int sb = ii * 256 + w * 64;                                               \
    gld_lds16(Wb + (size_t)((sb + l) >> 3) * 1024 + k0 + ((sb + l) & 7) * 8,  \
              &Ws[buf][sb * 8]); } }

  STAGE(0, 0); STAGE(1, 1);
  int cur = 0, wb = 2;

  for (int kt = 0; kt < 16; ++kt) {
    if (kt + 1 < 16) PIPE_BARRIER(6) else PIPE_BARRIER(0);
    if (kt + 2 < 16) STAGE(kt + 2, wb);
    __builtin_amdgcn_s_setprio(1);
#pragma unroll
    for (int kk = 0; kk < 2; ++kk) {
      int c0 = (kk * 32 + hi * 8) ^ rsw;
      bf16x8 af0 = *(const bf16x8*)&As[cur][(w * 32 + lo) * 64 + c0];
      bf16x8 af1 = *(const bf16x8*)&As[cur][(w * 32 + 16 + lo) * 64 + c0];
#pragma unroll
      for (int ni = 0; ni < 4; ++ni) {
        bf16x8 wf = *(const bf16x8*)&Ws[cur][(ni * 16 + lo) * 64 + c0];
        acc[0][ni] = __builtin_amdgcn_mfma_f32_16x16x32_bf16(af0, wf, acc[0][ni], 0, 0, 0);
        acc[1][ni] = __builtin_amdgcn_mfma_f32_16x16x32_bf16(af1, wf, acc[1][ni], 0, 0, 0);
      }
    }
    __builtin_amdgcn_s_setprio(0);
    cur = (cur == 2) ? 0 : cur + 1;
    wb = (wb == 2) ? 0 : wb + 1;
  }
#undef STAGE

  // epilogue: bn = head group (0-15 q, 16-19 k, 20-23 v)
  if (bn < 20) {
    int isq = (bn < 16);
    int h = isq ? bn : bn - 16;
    float sc = isq ? (qks[h] * (LOG2E / 64.0f)) : 1.0f;
    unsigned short* base = isq ? qb : kb;
    int nheads = isq ? NH_ : NKV_;
#pragma unroll
    for (int mi = 0; mi < 2; ++mi) {
#pragma unroll
      for (int r = 0; r < 4; ++r) {
        int row = bm * 128 + w * 32 + mi * 16 + hi * 4 + r;
        int b = row >> 11, t = row & 2047;
        float c = cosT[t * 16 + lo], s = sinT[t * 16 + lo];
        float a0 = acc[mi][0][r], a1 = acc[mi][1][r];
        __bf16* dp = (__bf16*)(base + ((size_t)(b * nheads + h) * T_ + t) * 64);
        int ts = isq ? 0 : (8 * (t & 7));  // K stored d-swizzled for attn LDS reads
        dp[lo ^ ts]        = (__bf16)((a0 * c - a1 * s) * sc);
        dp[(16 + lo) ^ ts] = (__bf16)((a0 * s + a1 * c) * sc);
        dp[(32 + lo) ^ ts] = (__bf16)(acc[mi][2][r] * sc);
        dp[(48 + lo) ^ ts] = (__bf16)(acc[mi][3][r] * sc);
      }
    }
  } else {
    int hv = bn - 20;
    float av[4];
#pragma unroll
    for (int j = 0; j < 4; ++j) av[j] = 1.0f / (1.0f + __expf(-vrl[hv * 4 + j]));
#pragma unroll
    for (int mi = 0; mi < 2; ++mi) {
      int t0g = bm * 128 + w * 32 + mi * 16 + hi * 4;
      int b = t0g >> 11, t0 = t0g & 2047;
#pragma unroll
      for (int ni = 0; ni < 4; ++ni) {
        int d = ni * 16 + lo;
#pragma unroll
        for (int j = 0; j < 4; ++j) {
          float a = av[j], na = 1.0f - a;
          const float* v0p = v0 + ((size_t)(b * NH_ + hv * 4 + j) * T_ + t0) * 64 + d;
          bf16x4 vv;
#pragma unroll
          for (int r = 0; r < 4; ++r)
            vv[r] = (__bf16)(na * acc[mi][ni][r] + a * v0p[(size_t)r * 64]);
          // v^T store: [b][h][d][t], t swizzled within 64-block by 8*(d&7)
          *(bf16x4*)((unsigned short*)vb + ((size_t)(b * NH_ + hv * 4 + j) * 64 + d) * T_ +
                     (t0 ^ (8 * (lo & 7)))) = vv;
        }
      }
    }
  }
}

// ---------------- proj GEMM (+ fused v0 passthrough copy blocks) ----------
__global__ __launch_bounds__(256) void k_gemm_proj(
    const unsigned short* __restrict__ A,
    const unsigned short* __restrict__ W,
    const float* __restrict__ v0,
    float* __restrict__ C, float* __restrict__ out2) {
  __shared__ __align__(16) unsigned short As[3][128 * 64];
  __shared__ __align__(16) unsigned short Ws[3][64 * 64];
  int tid = threadIdx.x;

  if (blockIdx.y >= 32) {  // v0 passthrough: 128 blocks x 256 thr x 32 float4
    int idx = ((blockIdx.y - 32) * 16 + blockIdx.x) * 256 + tid;
    const float4* src = (const float4*)v0;
    float4* dst = (float4*)out2;
#pragma unroll
    for (int i = 0; i < 32; ++i) dst[idx + i * 32768] = src[idx + i * 32768];
    return;
  }

  int w = tid >> 6, l = tid & 63, lo = l & 15, hi = l >> 4;
  int f = blockIdx.y * 16 + blockIdx.x;  // 512 gemm blocks
  int f2 = (f & 7) * 64 + (f >> 3);
  int bn = f2 & 15, bm = f2 >> 4;
  int rsw = (lo & 7) * 8;

  const unsigned short* Ab = A + (size_t)bm * 128 * 1024;
  const unsigned short* Wb = W + (size_t)bn * 64 * 1024;

  f32x4 acc[2][4];
#pragma unroll
  for (int mi = 0; mi < 2; ++mi)
#pragma unroll
    for (int ni = 0; ni < 4; ++ni) acc[mi][ni] = (f32x4){0.f, 0.f, 0.f, 0.f};

#define STAGE(kt, buf) {                                                       \
  int k0 = (kt) * 64;                                                         \
  _Pragma("unroll") for (int ii = 0; ii < 4; ++ii) {                          \
    int sb = ii * 256 + w * 64;                                               \
    gld_lds16(Ab + (size_t)((sb + l) >> 3) * 1024 + k0 + ((sb + l) & 7) * 8,  \
              &As[buf][sb * 8]); }                                            \
  _Pragma("unroll") for (int ii = 0; ii < 2; ++ii) {                          \
    int sb = ii * 256 + w * 64;                                               \
    gld_lds16(Wb + (size_t)((sb + l) >> 3) * 1024 + k0 + ((sb + l) & 7) * 8,  \
              &Ws[buf][sb * 8]); } }

  STAGE(0, 0); STAGE(1, 1);
  int cur = 0, wb = 2;

  for (int kt = 0; kt < 16; ++kt) {
    if (kt + 1 < 16) PIPE_BARRIER(6) else PIPE_BARRIER(0);
    if (kt + 2 < 16) STAGE(kt + 2, wb);
    __builtin_amdgcn_s_setprio(1);
#pragma unroll
    for (int kk = 0; kk < 2; ++kk) {
      int c0 = (kk * 32 + hi * 8) ^ rsw;
      bf16x8 af0 = *(const bf16x8*)&As[cur][(w * 32 + lo) * 64 + c0];
      bf16x8 af1 = *(const bf16x8*)&As[cur][(w * 32 + 16 + lo) * 64 + c0];
#pragma unroll
      for (int ni = 0; ni < 4; ++ni) {
        bf16x8 wf = *(const bf16x8*)&Ws[cur][(ni * 16 + lo) * 64 + c0];
        acc[0][ni] = __builtin_amdgcn_mfma_f32_16x16x32_bf16(af0, wf, acc[0][ni], 0, 0, 0);
        acc[1][ni] = __builtin_amdgcn_mfma_f32_16x16x32_bf16(af1, wf, acc[1][ni], 0, 0, 0);
      }
    }
    __builtin_amdgcn_s_setprio(0);
    cur = (cur == 2) ? 0 : cur + 1;
    wb = (wb == 2) ? 0 : wb + 1;
  }
#undef STAGE

#pragma unroll
  for (int mi = 0; mi < 2; ++mi) {
#pragma unroll
    for (int r = 0; r < 4; ++r) {
      int row = bm * 128 + w * 32 + mi * 16 + hi * 4 + r;
      float* cp = C + (size_t)row * D_ + bn * 64 + lo;
#pragma unroll
      for (int ni = 0; ni < 4; ++ni) cp[ni * 16] = acc[mi][ni][r];
    }
  }
}

// ---------------- flash attention: 8 waves, 3-deep K/V pipeline, counted vmcnt ---------
static __device__ __forceinline__ void stage_kv8(const unsigned short* Kb, const unsigned short* Vb,
                                                 int kv0, int w, int l,
                                                 unsigned short* KsB, unsigned short* VsB) {
  gld_lds16(Kb + (size_t)kv0 * 64 + w * 512 + l * 8, KsB + w * 512);
  gld_lds16(Vb + (size_t)(w * 8 + (l >> 3)) * T_ + kv0 + (l & 7) * 8, VsB + w * 512);
}

// online softmax in exp2 domain, defer-max (THR=8), per-lane partial lsum
__device__ __forceinline__ void softmax_state(f32x4 (&s)[4], float& m, float& lsum,
                                              f32x4 (&y)[4], unsigned short* PsW,
                                              int lo, int hi, int swz) {
  float a0 = fmax3(s[0][0], s[0][1], s[0][2]);
  float a1 = fmax3(s[0][3], s[1][0], s[1][1]);
  float a2 = fmax3(s[1][2], s[1][3], s[2][0]);
  float a3 = fmax3(s[2][1], s[2][2], s[2][3]);
  float a4 = fmax3(s[3][0], s[3][1], s[3][2]);
  float pm = fmaxf(fmax3(a0, a1, a2), fmax3(a3, a4, s[3][3]));
  if (!__all(pm <= m + 8.0f)) {  // rare after first tile
    pm = fmaxf(pm, __shfl_xor(pm, 16));
    pm = fmaxf(pm, __shfl_xor(pm, 32));
    float mnew = fmaxf(m, pm);
    float sc = fexp2(m - mnew);
    lsum *= sc;
#pragma unroll
    for (int r = 0; r < 4; ++r) {
      float scr = __shfl(sc, hi * 4 + r);
#pragma unroll
      for (int nf = 0; nf < 4; ++nf) y[nf][r] *= scr;
    }
    m = mnew;
  }
  float rs = 0.f;
#pragma unroll
  for (int nt = 0; nt < 4; ++nt) {
    float p0 = fexp2(s[nt][0] - m);
    float p1 = fexp2(s[nt][1] - m);
    float p2 = fexp2(s[nt][2] - m);
    float p3 = fexp2(s[nt][3] - m);
    rs += (p0 + p1) + (p2 + p3);
    bf16x4 pk;
    pk[0] = (__bf16)p0; pk[1] = (__bf16)p1; pk[2] = (__bf16)p2; pk[3] = (__bf16)p3;
    *(bf16x4*)(PsW + lo * 64 + ((nt * 16 + hi * 4) ^ swz)) = pk;
  }
  lsum += rs;
}

__global__ __launch_bounds__(512, 2) void k_attn(const unsigned short* __restrict__ Q,
                                                 const unsigned short* __restrict__ Kp,
                                                 const unsigned short* __restrict__ Vtp,
                                                 unsigned short* __restrict__ Y) {
  int p = blockIdx.x, h = blockIdx.y, b = blockIdx.z;
  if (b == 1) p = 15 - p;  // complementary pairing across the two dispatch halves
  int tid = threadIdx.x;
  int w = tid >> 6, l = tid & 63, lo = l & 15, hi = l >> 4;
  int kh = h >> 2;
  int qtA = p, qtB = 31 - p;
  int ntB = qtB + 1;                // >= 17
  int st = w >> 2, wq = w & 3;      // st: 0 = state B (waves 0-3), 1 = state A (waves 4-7)
  int qt = st ? qtA : qtB;
  int q0 = qt * 64 + wq * 16;
  int swz = 8 * (lo & 7);

  __shared__ __align__(16) unsigned short Ks[3][4096];
  __shared__ __align__(16) unsigned short Vs[3][4096];
  __shared__ __align__(16) unsigned short Ps[8192];  // 1024 shorts per wave
  unsigned short* PsW = &Ps[w * 1024];

  const unsigned short* Qb = Q + ((size_t)(b * NH_ + h) * T_) * 64;
  const unsigned short* Kb = Kp + ((size_t)(b * NKV_ + kh) * T_) * 64;
  const unsigned short* Vb = Vtp + ((size_t)(b * NH_ + h) * 64) * T_;

  bf16x8 q_0 = *(const bf16x8*)(Qb + (size_t)(q0 + lo) * 64 + hi * 8);
  bf16x8 q_1 = *(const bf16x8*)(Qb + (size_t)(q0 + lo) * 64 + 32 + hi * 8);

  f32x4 y[4];
#pragma unroll
  for (int nf = 0; nf < 4; ++nf) y[nf] = (f32x4){0.f, 0.f, 0.f, 0.f};
  float m = -INFINITY, lsum = 0.f;

  stage_kv8(Kb, Vb, 0, w, l, Ks[0], Vs[0]);
  stage_kv8(Kb, Vb, 64, w, l, Ks[1], Vs[1]);
  int cur = 0, wbuf = 2;

  for (int kt = 0; kt < ntB; ++kt) {
    if (kt + 1 < ntB) PIPE_BARRIER(2) else PIPE_BARRIER(0);
    if (kt + 2 < ntB) stage_kv8(Kb, Vb, (kt + 2) * 64, w, l, Ks[wbuf], Vs[wbuf]);

    if (kt <= qt) {
      int kv0 = kt * 64;
      const unsigned short* KsC = Ks[cur];
      const unsigned short* VsC = Vs[cur];

      // S^T = mfma(K, Q): D[key][q], q = lo, key = kv0 + nt*16 + hi*4 + r
      f32x4 s[4];
      __builtin_amdgcn_s_setprio(1);
#pragma unroll
      for (int nt = 0; nt < 4; ++nt) {
        int rrow = (nt * 16 + lo) * 64;
        int c0 = (hi * 8) ^ swz;
        bf16x8 kf0 = *(const bf16x8*)&KsC[rrow + c0];
        bf16x8 kf1 = *(const bf16x8*)&KsC[rrow + (c0 ^ 32)];
        f32x4 a = (f32x4){0.f, 0.f, 0.f, 0.f};
        a = __builtin_amdgcn_mfma_f32_16x16x32_bf16(kf0, q_0, a, 0, 0, 0);
        a = __builtin_amdgcn_mfma_f32_16x16x32_bf16(kf1, q_1, a, 0, 0, 0);
        s[nt] = a;
      }
      __builtin_amdgcn_s_setprio(0);

      if (kt == qt) {  // diagonal tile: causal mask
#pragma unroll
        for (int nt = 0; nt < 4; ++nt)
#pragma unroll
          for (int r = 0; r < 4; ++r)
            if (kv0 + nt * 16 + hi * 4 + r > q0 + lo) s[nt][r] = -1e30f;
      }

      softmax_state(s, m, lsum, y, PsW, lo, hi, swz);

      // PV: y[q][d] += P[q][k] * V[k][d]
      __builtin_amdgcn_s_setprio(1);
#pragma unroll
      for (int kc = 0; kc < 2; ++kc) {
        int pcol = (kc * 32 + hi * 8) ^ swz;
        bf16x8 pa = *(const bf16x8*)&PsW[lo * 64 + pcol];
#pragma unroll
        for (int nf = 0; nf < 4; ++nf) {
          bf16x8 vf = *(const bf16x8*)&VsC[(nf * 16 + lo) * 64 + pcol];
          y[nf] = __builtin_amdgcn_mfma_f32_16x16x32_bf16(pa, vf, y[nf], 0, 0, 0);
        }
      }
      __builtin_amdgcn_s_setprio(0);
    }

    cur = (cur == 2) ? 0 : cur + 1;
    wbuf = (wbuf == 2) ? 0 : wbuf + 1;
  }

  // epilogue: reduce per-lane partial sums, divide, store PRE-SWIZZLED y for proj
  lsum += __shfl_xor(lsum, 16);
  lsum += __shfl_xor(lsum, 32);
  float inv = frcp(lsum);
#pragma unroll
  for (int r = 0; r < 4; ++r) {
    float iv = __shfl(inv, hi * 4 + r);
    int t = q0 + hi * 4 + r;
    int sw = 8 * (t & 7);
    __bf16* yp = (__bf16*)(Y + ((size_t)(b * T_ + t)) * D_ + h * 64);
#pragma unroll
    for (int nf = 0; nf < 4; ++nf)
      yp[(nf * 16 + lo) ^ sw] = (__bf16)(y[nf][r] * iv);
  }
}

extern "C" void kernel_launch(void* const* d_in, const int* in_sizes, int n_in,
                              void* d_out, int out_size, void* d_ws, size_t ws_size,
                              hipStream_t stream) {
  const float* x     = (const float*)d_in[0];
  const float* cosT  = (const float*)d_in[1];
  const float* sinT  = (const float*)d_in[2];
  const float* v0    = (const float*)d_in[3];
  const float* Wqkv  = (const float*)d_in[4];
  const float* Wproj = (const float*)d_in[5];
  const float* vrl   = (const float*)d_in[6];
  const float* qks   = (const float*)d_in[7];
  float* out = (float*)d_out;

  char* ws = (char*)d_ws;
  unsigned short* xb     = (unsigned short*)ws;                   //  8388608 B (pre-swizzled)
  unsigned short* wqkvb  = (unsigned short*)(ws + 8388608);       //  3145728 B (pre-swizzled)
  unsigned short* wprojb = (unsigned short*)(ws + 11534336);      //  2097152 B (pre-swizzled)
  unsigned short* qb     = (unsigned short*)(ws + 13631488);      //  8388608 B
  unsigned short* kb     = (unsigned short*)(ws + 22020096);      //  2097152 B (d-swizzled)
  unsigned short* vb     = (unsigned short*)(ws + 24117248);      //  8388608 B (V^T swizzled)
  unsigned short* yb     = (unsigned short*)(ws + 32505856);      //  8388608 B (pre-swizzled)

  k_convert_all<<<3328, 256, 0, stream>>>(x, Wqkv, Wproj, xb, wqkvb, wprojb);

  k_gemm_qkv<<<dim3(24, 32), 256, 0, stream>>>(xb, wqkvb, cosT, sinT, v0, vrl, qks, qb, kb, vb);

  k_attn<<<dim3(16, NH_, B_), 512, 0, stream>>>(qb, kb, vb, yb);

  k_gemm_proj<<<dim3(16, 40), 256, 0, stream>>>(yb, wprojb, v0, out, out + 4194304);
}

// Round 11
// 91.900 us; speedup vs baseline: 1.0796x; 1.0796x over previous
//
#include <hip/hip_runtime.h>
#include <hip/hip_bf16.h>

#define B_   2
#define T_   2048
#define D_   1024
#define NH_  16
#define NKV_ 4
#define HD_  64
#define E_   1536  // (NH + 2*NKV) * HD
#define LOG2E 1.4426950408889634f

typedef __attribute__((ext_vector_type(8))) __bf16 bf16x8;
typedef __attribute__((ext_vector_type(4))) __bf16 bf16x4;
typedef __attribute__((ext_vector_type(4))) float f32x4;

// async global->LDS, 16B per lane. LDS dest = wave-uniform base + lane*16.
static __device__ __forceinline__ void gld_lds16(const unsigned short* g, unsigned short* l) {
  __builtin_amdgcn_global_load_lds(
      (const __attribute__((address_space(1))) unsigned int*)(unsigned long long)(const void*)g,
      (__attribute__((address_space(3))) unsigned int*)(unsigned int)(unsigned long long)(void*)l,
      16, 0, 0);
}

// raw hardware ops (avoid OCML guard sequences; args bounded, FTZ exact for us)
static __device__ __forceinline__ float fexp2(float x) {
  float r; asm("v_exp_f32 %0, %1" : "=v"(r) : "v"(x)); return r;
}
static __device__ __forceinline__ float fmax3(float a, float b, float c) {
  float r; asm("v_max3_f32 %0, %1, %2, %3" : "=v"(r) : "v"(a), "v"(b), "v"(c)); return r;
}
static __device__ __forceinline__ float frcp(float x) {
  float r; asm("v_rcp_f32 %0, %1" : "=v"(r) : "v"(x)); return r;
}

// counted-vmcnt barrier: loads stay in flight across the barrier (T3/T4, m201 pattern)
#define PIPE_BARRIER(N) {                                   \
  asm volatile("s_waitcnt vmcnt(" #N ")" ::: "memory");     \
  __builtin_amdgcn_s_barrier();                             \
  __builtin_amdgcn_sched_barrier(0); }

#define CVT8(dst, f0, f1) {                                                    \
  dst[0] = (__bf16)f0.x; dst[1] = (__bf16)f0.y;                               \
  dst[2] = (__bf16)f0.z; dst[3] = (__bf16)f0.w;                               \
  dst[4] = (__bf16)f1.x; dst[5] = (__bf16)f1.y;                               \
  dst[6] = (__bf16)f1.z; dst[7] = (__bf16)f1.w; }

// ---- fp32->bf16 convert, PRE-SWIZZLED: buf[n][c ^ 8*(n&7)] = src[n][c] ----
__global__ void k_convert_all(const float* __restrict__ x, const float* __restrict__ wq,
                              const float* __restrict__ wp,
                              unsigned short* __restrict__ xb, unsigned short* __restrict__ wqb,
                              unsigned short* __restrict__ wpb) {
  int i = blockIdx.x * blockDim.x + threadIdx.x;  // 851968 total groups of 8
  const float* src; unsigned short* dst; int j;
  if (i < 524288)      { src = x;  dst = xb;  j = i; }
  else if (i < 720896) { src = wq; dst = wqb; j = i - 524288; }
  else                 { src = wp; dst = wpb; j = i - 720896; }
  int n = j >> 7, c8 = (j & 127) * 8;
  const float4* p = (const float4*)(src + (size_t)n * 1024 + c8);
  float4 a = p[0], b = p[1];
  bf16x8 o; CVT8(o, a, b);
  *(bf16x8*)(dst + (size_t)n * 1024 + (c8 ^ ((n & 7) * 8))) = o;
}

// ---------------- QKV GEMM: 128x128 tile, 4 waves x 64x64, BK=64, 2-phase ------------
// pre-swizzled bf16 A and W via gld_lds; fused RoPE/scale/V-mix epilogue.
// grid (12, 32) = 384 blocks; wave's 64-col half = one head: hg = 2*bn + wn.
__global__ __launch_bounds__(256) void k_gemm_qkv(
    const unsigned short* __restrict__ A,   // pre-swizzled bf16 x
    const unsigned short* __restrict__ W,   // pre-swizzled bf16
    const float* __restrict__ cosT, const float* __restrict__ sinT,
    const float* __restrict__ v0,
    const float* __restrict__ vrl, const float* __restrict__ qks,
    unsigned short* __restrict__ qb, unsigned short* __restrict__ kb,
    unsigned short* __restrict__ vb) {
  __shared__ __align__(16) unsigned short As[2][128 * 64];
  __shared__ __align__(16) unsigned short Ws[2][128 * 64];
  int tid = threadIdx.x;
  int w = tid >> 6, l = tid & 63, lo = l & 15, hi = l >> 4;
  int wm = w >> 1, wn = w & 1;
  int f = blockIdx.y * 12 + blockIdx.x;           // 384 blocks, %8==0
  int f2 = (f & 7) * 48 + (f >> 3);               // XCD swizzle
  int bn = f2 % 12, bm = f2 / 12;
  int rsw = (lo & 7) * 8;                         // read-side swizzle

  const unsigned short* Ab = A + (size_t)bm * 128 * 1024;
  const unsigned short* Wb = W + (size_t)bn * 128 * 1024;

  f32x4 acc[4][4];
#pragma unroll
  for (int mi = 0; mi < 4; ++mi)
#pragma unroll
    for (int ni = 0; ni < 4; ++ni) acc[mi][ni] = (f32x4){0.f, 0.f, 0.f, 0.f};

#define STAGE(kt, buf) {                                                       \
  int k0 = (kt) * 64;                                                         \
  _Pragma("unroll") for (int ii = 0; ii < 4; ++ii) {                          \
    int sb = ii * 256 + tid;                                                  \
    gld_lds16(Ab + (size_t)(sb >> 3) * 1024 + k0 + (sb & 7) * 8,              \
              &As[buf][(sb & ~63) * 8]);                                      \
  }                                                                           \
  _Pragma("unroll") for (int ii = 0; ii < 4; ++ii) {                          \
    int sb = ii * 256 + tid;                                                  \
    gld_lds16(Wb + (size_t)(sb >> 3) * 1024 + k0 + (sb & 7) * 8,              \
              &Ws[buf][(sb & ~63) * 8]);                                      \
  } }

  STAGE(0, 0);
  __syncthreads();

  for (int kt = 0; kt < 16; ++kt) {
    int cur = kt & 1;
    bool pf = (kt + 1) < 16;
    if (pf) STAGE(kt + 1, cur ^ 1);
    __builtin_amdgcn_s_setprio(1);
#pragma unroll
    for (int kk = 0; kk < 2; ++kk) {
      int c0 = (kk * 32 + hi * 8) ^ rsw;
      bf16x8 af[4], wf[4];
#pragma unroll
      for (int mi = 0; mi < 4; ++mi)
        af[mi] = *(const bf16x8*)&As[cur][(wm * 64 + mi * 16 + lo) * 64 + c0];
#pragma unroll
      for (int ni = 0; ni < 4; ++ni)
        wf[ni] = *(const bf16x8*)&Ws[cur][(wn * 64 + ni * 16 + lo) * 64 + c0];
#pragma unroll
      for (int mi = 0; mi < 4; ++mi)
#pragma unroll
        for (int ni = 0; ni < 4; ++ni)
          acc[mi][ni] = __builtin_amdgcn_mfma_f32_16x16x32_bf16(af[mi], wf[ni], acc[mi][ni], 0, 0, 0);
    }
    __builtin_amdgcn_s_setprio(0);
    __syncthreads();
  }
#undef STAGE

  // epilogue: hg = 2*bn + wn = head group (0-15 q, 16-19 k, 20-23 v)
  int hg = bn * 2 + wn;
  if (hg < 20) {
    int isq = (hg < 16);
    int h = isq ? hg : hg - 16;
    float sc = isq ? (qks[h] * (LOG2E / 64.0f)) : 1.0f;
    unsigned short* base = isq ? qb : kb;
    int nheads = isq ? NH_ : NKV_;
#pragma unroll
    for (int mi = 0; mi < 4; ++mi) {
#pragma unroll
      for (int r = 0; r < 4; ++r) {
        int row = bm * 128 + wm * 64 + mi * 16 + hi * 4 + r;
        int b = row >> 11, t = row & 2047;
        float c = cosT[t * 16 + lo], s = sinT[t * 16 + lo];
        float a0 = acc[mi][0][r], a1 = acc[mi][1][r];
        __bf16* dp = (__bf16*)(base + ((size_t)(b * nheads + h) * T_ + t) * 64);
        int ts = isq ? 0 : (8 * (t & 7));  // K stored d-swizzled for attn LDS reads
        dp[lo ^ ts]        = (__bf16)((a0 * c - a1 * s) * sc);
        dp[(16 + lo) ^ ts] = (__bf16)((a0 * s + a1 * c) * sc);
        dp[(32 + lo) ^ ts] = (__bf16)(acc[mi][2][r] * sc);
        dp[(48 + lo) ^ ts] = (__bf16)(acc[mi][3][r] * sc);
      }
    }
  } else {
    int hv = hg - 20;
    float av[4];
#pragma unroll
    for (int j = 0; j < 4; ++j) av[j] = 1.0f / (1.0f + __expf(-vrl[hv * 4 + j]));
#pragma unroll
    for (int mi = 0; mi < 4; ++mi) {
      int t0g = bm * 128 + wm * 64 + mi * 16 + hi * 4;
      int b = t0g >> 11, t0 = t0g & 2047;
#pragma unroll
      for (int ni = 0; ni < 4; ++ni) {
        int d = ni * 16 + lo;
#pragma unroll
        for (int j = 0; j < 4; ++j) {
          float a = av[j], na = 1.0f - a;
          const float* v0p = v0 + ((size_t)(b * NH_ + hv * 4 + j) * T_ + t0) * 64 + d;
          bf16x4 vv;
#pragma unroll
          for (int r = 0; r < 4; ++r)
            vv[r] = (__bf16)(na * acc[mi][ni][r] + a * v0p[(size_t)r * 64]);
          // v^T store: [b][h][d][t], t swizzled within 64-block by 8*(d&7)
          *(bf16x4*)((unsigned short*)vb + ((size_t)(b * NH_ + hv * 4 + j) * 64 + d) * T_ +
                     (t0 ^ (8 * (lo & 7)))) = vv;
        }
      }
    }
  }
}

// ---------------- proj GEMM: 128x128 tile (+ fused v0 passthrough copy blocks) ----------
__global__ __launch_bounds__(256) void k_gemm_proj(
    const unsigned short* __restrict__ A,
    const unsigned short* __restrict__ W,
    const float* __restrict__ v0,
    float* __restrict__ C, float* __restrict__ out2) {
  __shared__ __align__(16) unsigned short As[2][128 * 64];
  __shared__ __align__(16) unsigned short Ws[2][128 * 64];
  int tid = threadIdx.x;

  if (blockIdx.y >= 32) {  // v0 passthrough: 128 blocks x 256 thr x 32 float4
    int idx = ((blockIdx.y - 32) * 8 + blockIdx.x) * 256 + tid;
    const float4* src = (const float4*)v0;
    float4* dst = (float4*)out2;
#pragma unroll
    for (int i = 0; i < 32; ++i) dst[idx + i * 32768] = src[idx + i * 32768];
    return;
  }

  int w = tid >> 6, l = tid & 63, lo = l & 15, hi = l >> 4;
  int wm = w >> 1, wn = w & 1;
  int f = blockIdx.y * 8 + blockIdx.x;  // 256 gemm blocks
  int f2 = (f & 7) * 32 + (f >> 3);
  int bn = f2 & 7, bm = f2 >> 3;
  int rsw = (lo & 7) * 8;

  const unsigned short* Ab = A + (size_t)bm * 128 * 1024;
  const unsigned short* Wb = W + (size_t)bn * 128 * 1024;

  f32x4 acc[4][4];
#pragma unroll
  for (int mi = 0; mi < 4; ++mi)
#pragma unroll
    for (int ni = 0; ni < 4; ++ni) acc[mi][ni] = (f32x4){0.f, 0.f, 0.f, 0.f};

#define STAGE(kt, buf) {                                                       \
  int k0 = (kt) * 64;                                                         \
  _Pragma("unroll") for (int ii = 0; ii < 4; ++ii) {                          \
    int sb = ii * 256 + tid;                                                  \
    gld_lds16(Ab + (size_t)(sb >> 3) * 1024 + k0 + (sb & 7) * 8,              \
              &As[buf][(sb & ~63) * 8]);                                      \
  }                                                                           \
  _Pragma("unroll") for (int ii = 0; ii < 4; ++ii) {                          \
    int sb = ii * 256 + tid;                                                  \
    gld_lds16(Wb + (size_t)(sb >> 3) * 1024 + k0 + (sb & 7) * 8,              \
              &Ws[buf][(sb & ~63) * 8]);                                      \
  } }

  STAGE(0, 0);
  __syncthreads();
  for (int kt = 0; kt < 16; ++kt) {
    int cur = kt & 1;
    bool pf = (kt + 1) < 16;
    if (pf) STAGE(kt + 1, cur ^ 1);
    __builtin_amdgcn_s_setprio(1);
#pragma unroll
    for (int kk = 0; kk < 2; ++kk) {
      int c0 = (kk * 32 + hi * 8) ^ rsw;
      bf16x8 af[4], wf[4];
#pragma unroll
      for (int mi = 0; mi < 4; ++mi)
        af[mi] = *(const bf16x8*)&As[cur][(wm * 64 + mi * 16 + lo) * 64 + c0];
#pragma unroll
      for (int ni = 0; ni < 4; ++ni)
        wf[ni] = *(const bf16x8*)&Ws[cur][(wn * 64 + ni * 16 + lo) * 64 + c0];
#pragma unroll
      for (int mi = 0; mi < 4; ++mi)
#pragma unroll
        for (int ni = 0; ni < 4; ++ni)
          acc[mi][ni] = __builtin_amdgcn_mfma_f32_16x16x32_bf16(af[mi], wf[ni], acc[mi][ni], 0, 0, 0);
    }
    __builtin_amdgcn_s_setprio(0);
    __syncthreads();
  }
#undef STAGE

#pragma unroll
  for (int mi = 0; mi < 4; ++mi) {
#pragma unroll
    for (int r = 0; r < 4; ++r) {
      int row = bm * 128 + wm * 64 + mi * 16 + hi * 4 + r;
      float* cp = C + (size_t)row * D_ + bn * 128 + wn * 64 + lo;
#pragma unroll
      for (int ni = 0; ni < 4; ++ni) cp[ni * 16] = acc[mi][ni][r];
    }
  }
}

// ---------------- flash attention: 8 waves, 3-deep K/V pipeline, counted vmcnt ---------
static __device__ __forceinline__ void stage_kv8(const unsigned short* Kb, const unsigned short* Vb,
                                                 int kv0, int w, int l,
                                                 unsigned short* KsB, unsigned short* VsB) {
  gld_lds16(Kb + (size_t)kv0 * 64 + w * 512 + l * 8, KsB + w * 512);
  gld_lds16(Vb + (size_t)(w * 8 + (l >> 3)) * T_ + kv0 + (l & 7) * 8, VsB + w * 512);
}

// online softmax in exp2 domain, defer-max (THR=8), per-lane partial lsum
__device__ __forceinline__ void softmax_state(f32x4 (&s)[4], float& m, float& lsum,
                                              f32x4 (&y)[4], unsigned short* PsW,
                                              int lo, int hi, int swz) {
  float a0 = fmax3(s[0][0], s[0][1], s[0][2]);
  float a1 = fmax3(s[0][3], s[1][0], s[1][1]);
  float a2 = fmax3(s[1][2], s[1][3], s[2][0]);
  float a3 = fmax3(s[2][1], s[2][2], s[2][3]);
  float a4 = fmax3(s[3][0], s[3][1], s[3][2]);
  float pm = fmaxf(fmax3(a0, a1, a2), fmax3(a3, a4, s[3][3]));
  if (!__all(pm <= m + 8.0f)) {  // rare after first tile
    pm = fmaxf(pm, __shfl_xor(pm, 16));
    pm = fmaxf(pm, __shfl_xor(pm, 32));
    float mnew = fmaxf(m, pm);
    float sc = fexp2(m - mnew);
    lsum *= sc;
#pragma unroll
    for (int r = 0; r < 4; ++r) {
      float scr = __shfl(sc, hi * 4 + r);
#pragma unroll
      for (int nf = 0; nf < 4; ++nf) y[nf][r] *= scr;
    }
    m = mnew;
  }
  float rs = 0.f;
#pragma unroll
  for (int nt = 0; nt < 4; ++nt) {
    float p0 = fexp2(s[nt][0] - m);
    float p1 = fexp2(s[nt][1] - m);
    float p2 = fexp2(s[nt][2] - m);
    float p3 = fexp2(s[nt][3] - m);
    rs += (p0 + p1) + (p2 + p3);
    bf16x4 pk;
    pk[0] = (__bf16)p0; pk[1] = (__bf16)p1; pk[2] = (__bf16)p2; pk[3] = (__bf16)p3;
    *(bf16x4*)(PsW + lo * 64 + ((nt * 16 + hi * 4) ^ swz)) = pk;
  }
  lsum += rs;
}

__global__ __launch_bounds__(512, 2) void k_attn(const unsigned short* __restrict__ Q,
                                                 const unsigned short* __restrict__ Kp,
                                                 const unsigned short* __restrict__ Vtp,
                                                 unsigned short* __restrict__ Y) {
  int p = blockIdx.x, h = blockIdx.y, b = blockIdx.z;
  if (b == 1) p = 15 - p;  // complementary pairing across the two dispatch halves
  int tid = threadIdx.x;
  int w = tid >> 6, l = tid & 63, lo = l & 15, hi = l >> 4;
  int kh = h >> 2;
  int qtA = p, qtB = 31 - p;
  int ntB = qtB + 1;                // >= 17
  int st = w >> 2, wq = w & 3;      // st: 0 = state B (waves 0-3), 1 = state A (waves 4-7)
  int qt = st ? qtA : qtB;
  int q0 = qt * 64 + wq * 16;
  int swz = 8 * (lo & 7);

  __shared__ __align__(16) unsigned short Ks[3][4096];
  __shared__ __align__(16) unsigned short Vs[3][4096];
  __shared__ __align__(16) unsigned short Ps[8192];  // 1024 shorts per wave
  unsigned short* PsW = &Ps[w * 1024];

  const unsigned short* Qb = Q + ((size_t)(b * NH_ + h) * T_) * 64;
  const unsigned short* Kb = Kp + ((size_t)(b * NKV_ + kh) * T_) * 64;
  const unsigned short* Vb = Vtp + ((size_t)(b * NH_ + h) * 64) * T_;

  bf16x8 q_0 = *(const bf16x8*)(Qb + (size_t)(q0 + lo) * 64 + hi * 8);
  bf16x8 q_1 = *(const bf16x8*)(Qb + (size_t)(q0 + lo) * 64 + 32 + hi * 8);

  f32x4 y[4];
#pragma unroll
  for (int nf = 0; nf < 4; ++nf) y[nf] = (f32x4){0.f, 0.f, 0.f, 0.f};
  float m = -INFINITY, lsum = 0.f;

  stage_kv8(Kb, Vb, 0, w, l, Ks[0], Vs[0]);
  stage_kv8(Kb, Vb, 64, w, l, Ks[1], Vs[1]);
  int cur = 0, wbuf = 2;

  for (int kt = 0; kt < ntB; ++kt) {
    if (kt + 1 < ntB) PIPE_BARRIER(2) else PIPE_BARRIER(0);
    if (kt + 2 < ntB) stage_kv8(Kb, Vb, (kt + 2) * 64, w, l, Ks[wbuf], Vs[wbuf]);

    if (kt <= qt) {
      int kv0 = kt * 64;
      const unsigned short* KsC = Ks[cur];
      const unsigned short* VsC = Vs[cur];

      // S^T = mfma(K, Q): D[key][q], q = lo, key = kv0 + nt*16 + hi*4 + r
      f32x4 s[4];
      __builtin_amdgcn_s_setprio(1);
#pragma unroll
      for (int nt = 0; nt < 4; ++nt) {
        int rrow = (nt * 16 + lo) * 64;
        int c0 = (hi * 8) ^ swz;
        bf16x8 kf0 = *(const bf16x8*)&KsC[rrow + c0];
        bf16x8 kf1 = *(const bf16x8*)&KsC[rrow + (c0 ^ 32)];
        f32x4 a = (f32x4){0.f, 0.f, 0.f, 0.f};
        a = __builtin_amdgcn_mfma_f32_16x16x32_bf16(kf0, q_0, a, 0, 0, 0);
        a = __builtin_amdgcn_mfma_f32_16x16x32_bf16(kf1, q_1, a, 0, 0, 0);
        s[nt] = a;
      }
      __builtin_amdgcn_s_setprio(0);

      if (kt == qt) {  // diagonal tile: causal mask
#pragma unroll
        for (int nt = 0; nt < 4; ++nt)
#pragma unroll
          for (int r = 0; r < 4; ++r)
            if (kv0 + nt * 16 + hi * 4 + r > q0 + lo) s[nt][r] = -1e30f;
      }

      softmax_state(s, m, lsum, y, PsW, lo, hi, swz);

      // PV: y[q][d] += P[q][k] * V[k][d]
      __builtin_amdgcn_s_setprio(1);
#pragma unroll
      for (int kc = 0; kc < 2; ++kc) {
        int pcol = (kc * 32 + hi * 8) ^ swz;
        bf16x8 pa = *(const bf16x8*)&PsW[lo * 64 + pcol];
#pragma unroll
        for (int nf = 0; nf < 4; ++nf) {
          bf16x8 vf = *(const bf16x8*)&VsC[(nf * 16 + lo) * 64 + pcol];
          y[nf] = __builtin_amdgcn_mfma_f32_16x16x32_bf16(pa, vf, y[nf], 0, 0, 0);
        }
      }
      __builtin_amdgcn_s_setprio(0);
    }

    cur = (cur == 2) ? 0 : cur + 1;
    wbuf = (wbuf == 2) ? 0 : wbuf + 1;
  }

  // epilogue: reduce per-lane partial sums, divide, store PRE-SWIZZLED y for proj
  lsum += __shfl_xor(lsum, 16);
  lsum += __shfl_xor(lsum, 32);
  float inv = frcp(lsum);
#pragma unroll
  for (int r = 0; r < 4; ++r) {
    float iv = __shfl(inv, hi * 4 + r);
    int t = q0 + hi * 4 + r;
    int sw = 8 * (t & 7);
    __bf16* yp = (__bf16*)(Y + ((size_t)(b * T_ + t)) * D_ + h * 64);
#pragma unroll
    for (int nf = 0; nf < 4; ++nf)
      yp[(nf * 16 + lo) ^ sw] = (__bf16)(y[nf][r] * iv);
  }
}

extern "C" void kernel_launch(void* const* d_in, const int* in_sizes, int n_in,
                              void* d_out, int out_size, void* d_ws, size_t ws_size,
                              hipStream_t stream) {
  const float* x     = (const float*)d_in[0];
  const float* cosT  = (const float*)d_in[1];
  const float* sinT  = (const float*)d_in[2];
  const float* v0    = (const float*)d_in[3];
  const float* Wqkv  = (const float*)d_in[4];
  const float* Wproj = (const float*)d_in[5];
  const float* vrl   = (const float*)d_in[6];
  const float* qks   = (const float*)d_in[7];
  float* out = (float*)d_out;

  char* ws = (char*)d_ws;
  unsigned short* xb     = (unsigned short*)ws;                   //  8388608 B (pre-swizzled)
  unsigned short* wqkvb  = (unsigned short*)(ws + 8388608);       //  3145728 B (pre-swizzled)
  unsigned short* wprojb = (unsigned short*)(ws + 11534336);      //  2097152 B (pre-swizzled)
  unsigned short* qb     = (unsigned short*)(ws + 13631488);      //  8388608 B
  unsigned short* kb     = (unsigned short*)(ws + 22020096);      //  2097152 B (d-swizzled)
  unsigned short* vb     = (unsigned short*)(ws + 24117248);      //  8388608 B (V^T swizzled)
  unsigned short* yb     = (unsigned short*)(ws + 32505856);      //  8388608 B (pre-swizzled)

  k_convert_all<<<3328, 256, 0, stream>>>(x, Wqkv, Wproj, xb, wqkvb, wprojb);

  k_gemm_qkv<<<dim3(12, 32), 256, 0, stream>>>(xb, wqkvb, cosT, sinT, v0, vrl, qks, qb, kb, vb);

  k_attn<<<dim3(16, NH_, B_), 512, 0, stream>>>(qb, kb, vb, yb);

  k_gemm_proj<<<dim3(8, 48), 256, 0, stream>>>(yb, wprojb, v0, out, out + 4194304);
}

// Round 14
// 91.674 us; speedup vs baseline: 1.0822x; 1.0025x over previous
//
#include <hip/hip_runtime.h>
#include <hip/hip_bf16.h>

#define B_   2
#define T_   2048
#define D_   1024
#define NH_  16
#define NKV_ 4
#define HD_  64
#define E_   1536  // (NH + 2*NKV) * HD
#define LOG2E 1.4426950408889634f

typedef __attribute__((ext_vector_type(8))) __bf16 bf16x8;
typedef __attribute__((ext_vector_type(4))) __bf16 bf16x4;
typedef __attribute__((ext_vector_type(4))) float f32x4;

// async global->LDS, 16B per lane. LDS dest = wave-uniform base + lane*16.
static __device__ __forceinline__ void gld_lds16(const unsigned short* g, unsigned short* l) {
  __builtin_amdgcn_global_load_lds(
      (const __attribute__((address_space(1))) unsigned int*)(unsigned long long)(const void*)g,
      (__attribute__((address_space(3))) unsigned int*)(unsigned int)(unsigned long long)(void*)l,
      16, 0, 0);
}

// raw hardware ops (avoid OCML guard sequences; args bounded, FTZ exact for us)
static __device__ __forceinline__ float fexp2(float x) {
  float r; asm("v_exp_f32 %0, %1" : "=v"(r) : "v"(x)); return r;
}
static __device__ __forceinline__ float fmax3(float a, float b, float c) {
  float r; asm("v_max3_f32 %0, %1, %2, %3" : "=v"(r) : "v"(a), "v"(b), "v"(c)); return r;
}
static __device__ __forceinline__ float frcp(float x) {
  float r; asm("v_rcp_f32 %0, %1" : "=v"(r) : "v"(x)); return r;
}

// counted-vmcnt barrier: loads stay in flight across the barrier (T3/T4, m201 pattern)
#define PIPE_BARRIER(N) {                                   \
  asm volatile("s_waitcnt vmcnt(" #N ")" ::: "memory");     \
  __builtin_amdgcn_s_barrier();                             \
  __builtin_amdgcn_sched_barrier(0); }

#define CVT8(dst, f0, f1) {                                                    \
  dst[0] = (__bf16)f0.x; dst[1] = (__bf16)f0.y;                               \
  dst[2] = (__bf16)f0.z; dst[3] = (__bf16)f0.w;                               \
  dst[4] = (__bf16)f1.x; dst[5] = (__bf16)f1.y;                               \
  dst[6] = (__bf16)f1.z; dst[7] = (__bf16)f1.w; }

// ---- fp32->bf16 convert, PRE-SWIZZLED: buf[n][c ^ 8*(n&7)] = src[n][c] ----
__global__ void k_convert_all(const float* __restrict__ x, const float* __restrict__ wq,
                              const float* __restrict__ wp,
                              unsigned short* __restrict__ xb, unsigned short* __restrict__ wqb,
                              unsigned short* __restrict__ wpb) {
  int i = blockIdx.x * blockDim.x + threadIdx.x;  // 851968 total groups of 8
  const float* src; unsigned short* dst; int j;
  if (i < 524288)      { src = x;  dst = xb;  j = i; }
  else if (i < 720896) { src = wq; dst = wqb; j = i - 524288; }
  else                 { src = wp; dst = wpb; j = i - 720896; }
  int n = j >> 7, c8 = (j & 127) * 8;
  const float4* p = (const float4*)(src + (size_t)n * 1024 + c8);
  float4 a = p[0], b = p[1];
  bf16x8 o; CVT8(o, a, b);
  *(bf16x8*)(dst + (size_t)n * 1024 + (c8 ^ ((n & 7) * 8))) = o;
}

// ---------------- QKV GEMM: 128x128 tile, 4 waves x 64x64, BK=64, 2-phase ------------
__global__ __launch_bounds__(256) void k_gemm_qkv(
    const unsigned short* __restrict__ A,   // pre-swizzled bf16 x
    const unsigned short* __restrict__ W,   // pre-swizzled bf16
    const float* __restrict__ cosT, const float* __restrict__ sinT,
    const float* __restrict__ v0,
    const float* __restrict__ vrl, const float* __restrict__ qks,
    unsigned short* __restrict__ qb, unsigned short* __restrict__ kb,
    unsigned short* __restrict__ vb) {
  __shared__ __align__(16) unsigned short As[2][128 * 64];
  __shared__ __align__(16) unsigned short Ws[2][128 * 64];
  int tid = threadIdx.x;
  int w = tid >> 6, l = tid & 63, lo = l & 15, hi = l >> 4;
  int wm = w >> 1, wn = w & 1;
  int f = blockIdx.y * 12 + blockIdx.x;           // 384 blocks, %8==0
  int f2 = (f & 7) * 48 + (f >> 3);               // XCD swizzle
  int bn = f2 % 12, bm = f2 / 12;
  int rsw = (lo & 7) * 8;                         // read-side swizzle

  const unsigned short* Ab = A + (size_t)bm * 128 * 1024;
  const unsigned short* Wb = W + (size_t)bn * 128 * 1024;

  f32x4 acc[4][4];
#pragma unroll
  for (int mi = 0; mi < 4; ++mi)
#pragma unroll
    for (int ni = 0; ni < 4; ++ni) acc[mi][ni] = (f32x4){0.f, 0.f, 0.f, 0.f};

#define STAGE(kt, buf) {                                                       \
  int k0 = (kt) * 64;                                                         \
  _Pragma("unroll") for (int ii = 0; ii < 4; ++ii) {                          \
    int sb = ii * 256 + tid;                                                  \
    gld_lds16(Ab + (size_t)(sb >> 3) * 1024 + k0 + (sb & 7) * 8,              \
              &As[buf][(sb & ~63) * 8]);                                      \
  }                                                                           \
  _Pragma("unroll") for (int ii = 0; ii < 4; ++ii) {                          \
    int sb = ii * 256 + tid;                                                  \
    gld_lds16(Wb + (size_t)(sb >> 3) * 1024 + k0 + (sb & 7) * 8,              \
              &Ws[buf][(sb & ~63) * 8]);                                      \
  } }

  STAGE(0, 0);
  __syncthreads();

  for (int kt = 0; kt < 16; ++kt) {
    int cur = kt & 1;
    bool pf = (kt + 1) < 16;
    if (pf) STAGE(kt + 1, cur ^ 1);
    __builtin_amdgcn_s_setprio(1);
#pragma unroll
    for (int kk = 0; kk < 2; ++kk) {
      int c0 = (kk * 32 + hi * 8) ^ rsw;
      bf16x8 af[4], wf[4];
#pragma unroll
      for (int mi = 0; mi < 4; ++mi)
        af[mi] = *(const bf16x8*)&As[cur][(wm * 64 + mi * 16 + lo) * 64 + c0];
#pragma unroll
      for (int ni = 0; ni < 4; ++ni)
        wf[ni] = *(const bf16x8*)&Ws[cur][(wn * 64 + ni * 16 + lo) * 64 + c0];
#pragma unroll
      for (int mi = 0; mi < 4; ++mi)
#pragma unroll
        for (int ni = 0; ni < 4; ++ni)
          acc[mi][ni] = __builtin_amdgcn_mfma_f32_16x16x32_bf16(af[mi], wf[ni], acc[mi][ni], 0, 0, 0);
    }
    __builtin_amdgcn_s_setprio(0);
    __syncthreads();
  }
#undef STAGE

  // epilogue: hg = 2*bn + wn = head group (0-15 q, 16-19 k, 20-23 v)
  int hg = bn * 2 + wn;
  if (hg < 20) {
    int isq = (hg < 16);
    int h = isq ? hg : hg - 16;
    float sc = isq ? (qks[h] * (LOG2E / 64.0f)) : 1.0f;
    unsigned short* base = isq ? qb : kb;
    int nheads = isq ? NH_ : NKV_;
#pragma unroll
    for (int mi = 0; mi < 4; ++mi) {
#pragma unroll
      for (int r = 0; r < 4; ++r) {
        int row = bm * 128 + wm * 64 + mi * 16 + hi * 4 + r;
        int b = row >> 11, t = row & 2047;
        float c = cosT[t * 16 + lo], s = sinT[t * 16 + lo];
        float a0 = acc[mi][0][r], a1 = acc[mi][1][r];
        __bf16* dp = (__bf16*)(base + ((size_t)(b * nheads + h) * T_ + t) * 64);
        int ts = isq ? 0 : (8 * (t & 7));  // K stored d-swizzled for attn LDS reads
        dp[lo ^ ts]        = (__bf16)((a0 * c - a1 * s) * sc);
        dp[(16 + lo) ^ ts] = (__bf16)((a0 * s + a1 * c) * sc);
        dp[(32 + lo) ^ ts] = (__bf16)(acc[mi][2][r] * sc);
        dp[(48 + lo) ^ ts] = (__bf16)(acc[mi][3][r] * sc);
      }
    }
  } else {
    int hv = hg - 20;
    float av[4];
#pragma unroll
    for (int j = 0; j < 4; ++j) av[j] = 1.0f / (1.0f + __expf(-vrl[hv * 4 + j]));
#pragma unroll
    for (int mi = 0; mi < 4; ++mi) {
      int t0g = bm * 128 + wm * 64 + mi * 16 + hi * 4;
      int b = t0g >> 11, t0 = t0g & 2047;
#pragma unroll
      for (int ni = 0; ni < 4; ++ni) {
        int d = ni * 16 + lo;
#pragma unroll
        for (int j = 0; j < 4; ++j) {
          float a = av[j], na = 1.0f - a;
          const float* v0p = v0 + ((size_t)(b * NH_ + hv * 4 + j) * T_ + t0) * 64 + d;
          bf16x4 vv;
#pragma unroll
          for (int r = 0; r < 4; ++r)
            vv[r] = (__bf16)(na * acc[mi][ni][r] + a * v0p[(size_t)r * 64]);
          // v^T store: [b][h][d][t], t swizzled within 64-block by 8*(d&7)
          *(bf16x4*)((unsigned short*)vb + ((size_t)(b * NH_ + hv * 4 + j) * 64 + d) * T_ +
                     (t0 ^ (8 * (lo & 7)))) = vv;
        }
      }
    }
  }
}

// ---------------- proj GEMM: 128x128 tile (+ fused v0 passthrough copy blocks) ----------
__global__ __launch_bounds__(256) void k_gemm_proj(
    const unsigned short* __restrict__ A,
    const unsigned short* __restrict__ W,
    const float* __restrict__ v0,
    float* __restrict__ C, float* __restrict__ out2) {
  __shared__ __align__(16) unsigned short As[2][128 * 64];
  __shared__ __align__(16) unsigned short Ws[2][128 * 64];
  int tid = threadIdx.x;

  if (blockIdx.y >= 32) {  // v0 passthrough: 128 blocks x 256 thr x 32 float4
    int idx = ((blockIdx.y - 32) * 8 + blockIdx.x) * 256 + tid;
    const float4* src = (const float4*)v0;
    float4* dst = (float4*)out2;
#pragma unroll
    for (int i = 0; i < 32; ++i) dst[idx + i * 32768] = src[idx + i * 32768];
    return;
  }

  int w = tid >> 6, l = tid & 63, lo = l & 15, hi = l >> 4;
  int wm = w >> 1, wn = w & 1;
  int f = blockIdx.y * 8 + blockIdx.x;  // 256 gemm blocks
  int f2 = (f & 7) * 32 + (f >> 3);
  int bn = f2 & 7, bm = f2 >> 3;
  int rsw = (lo & 7) * 8;

  const unsigned short* Ab = A + (size_t)bm * 128 * 1024;
  const unsigned short* Wb = W + (size_t)bn * 128 * 1024;

  f32x4 acc[4][4];
#pragma unroll
  for (int mi = 0; mi < 4; ++mi)
#pragma unroll
    for (int ni = 0; ni < 4; ++ni) acc[mi][ni] = (f32x4){0.f, 0.f, 0.f, 0.f};

#define STAGE(kt, buf) {                                                       \
  int k0 = (kt) * 64;                                                         \
  _Pragma("unroll") for (int ii = 0; ii < 4; ++ii) {                          \
    int sb = ii * 256 + tid;                                                  \
    gld_lds16(Ab + (size_t)(sb >> 3) * 1024 + k0 + (sb & 7) * 8,              \
              &As[buf][(sb & ~63) * 8]);                                      \
  }                                                                           \
  _Pragma("unroll") for (int ii = 0; ii < 4; ++ii) {                          \
    int sb = ii * 256 + tid;                                                  \
    gld_lds16(Wb + (size_t)(sb >> 3) * 1024 + k0 + (sb & 7) * 8,              \
              &Ws[buf][(sb & ~63) * 8]);                                      \
  } }

  STAGE(0, 0);
  __syncthreads();
  for (int kt = 0; kt < 16; ++kt) {
    int cur = kt & 1;
    bool pf = (kt + 1) < 16;
    if (pf) STAGE(kt + 1, cur ^ 1);
    __builtin_amdgcn_s_setprio(1);
#pragma unroll
    for (int kk = 0; kk < 2; ++kk) {
      int c0 = (kk * 32 + hi * 8) ^ rsw;
      bf16x8 af[4], wf[4];
#pragma unroll
      for (int mi = 0; mi < 4; ++mi)
        af[mi] = *(const bf16x8*)&As[cur][(wm * 64 + mi * 16 + lo) * 64 + c0];
#pragma unroll
      for (int ni = 0; ni < 4; ++ni)
        wf[ni] = *(const bf16x8*)&Ws[cur][(wn * 64 + ni * 16 + lo) * 64 + c0];
#pragma unroll
      for (int mi = 0; mi < 4; ++mi)
#pragma unroll
        for (int ni = 0; ni < 4; ++ni)
          acc[mi][ni] = __builtin_amdgcn_mfma_f32_16x16x32_bf16(af[mi], wf[ni], acc[mi][ni], 0, 0, 0);
    }
    __builtin_amdgcn_s_setprio(0);
    __syncthreads();
  }
#undef STAGE

#pragma unroll
  for (int mi = 0; mi < 4; ++mi) {
#pragma unroll
    for (int r = 0; r < 4; ++r) {
      int row = bm * 128 + wm * 64 + mi * 16 + hi * 4 + r;
      float* cp = C + (size_t)row * D_ + bn * 128 + wn * 64 + lo;
#pragma unroll
      for (int ni = 0; ni < 4; ++ni) cp[ni * 16] = acc[mi][ni][r];
    }
  }
}

// ---------------- flash attention: 8 waves, 3-deep K/V pipeline, counted vmcnt ---------
static __device__ __forceinline__ void stage_kv8(const unsigned short* Kb, const unsigned short* Vb,
                                                 int kv0, int w, int l,
                                                 unsigned short* KsB, unsigned short* VsB) {
  gld_lds16(Kb + (size_t)kv0 * 64 + w * 512 + l * 8, KsB + w * 512);
  gld_lds16(Vb + (size_t)(w * 8 + (l >> 3)) * T_ + kv0 + (l & 7) * 8, VsB + w * 512);
}

// online softmax in exp2 domain, defer-max (THR=8), per-lane partial lsum
__device__ __forceinline__ void softmax_state(f32x4 (&s)[4], float& m, float& lsum,
                                              f32x4 (&y)[4], unsigned short* PsW,
                                              int lo, int hi, int swz) {
  float a0 = fmax3(s[0][0], s[0][1], s[0][2]);
  float a1 = fmax3(s[0][3], s[1][0], s[1][1]);
  float a2 = fmax3(s[1][2], s[1][3], s[2][0]);
  float a3 = fmax3(s[2][1], s[2][2], s[2][3]);
  float a4 = fmax3(s[3][0], s[3][1], s[3][2]);
  float pm = fmaxf(fmax3(a0, a1, a2), fmax3(a3, a4, s[3][3]));
  if (!__all(pm <= m + 8.0f)) {  // rare after first tile
    pm = fmaxf(pm, __shfl_xor(pm, 16));
    pm = fmaxf(pm, __shfl_xor(pm, 32));
    float mnew = fmaxf(m, pm);
    float sc = fexp2(m - mnew);
    lsum *= sc;
#pragma unroll
    for (int r = 0; r < 4; ++r) {
      float scr = __shfl(sc, hi * 4 + r);
#pragma unroll
      for (int nf = 0; nf < 4; ++nf) y[nf][r] *= scr;
    }
    m = mnew;
  }
  float rs = 0.f;
#pragma unroll
  for (int nt = 0; nt < 4; ++nt) {
    float p0 = fexp2(s[nt][0] - m);
    float p1 = fexp2(s[nt][1] - m);
    float p2 = fexp2(s[nt][2] - m);
    float p3 = fexp2(s[nt][3] - m);
    rs += (p0 + p1) + (p2 + p3);
    bf16x4 pk;
    pk[0] = (__bf16)p0; pk[1] = (__bf16)p1; pk[2] = (__bf16)p2; pk[3] = (__bf16)p3;
    *(bf16x4*)(PsW + lo * 64 + ((nt * 16 + hi * 4) ^ swz)) = pk;
  }
  lsum += rs;
}

__global__ __launch_bounds__(512, 2) void k_attn(const unsigned short* __restrict__ Q,
                                                 const unsigned short* __restrict__ Kp,
                                                 const unsigned short* __restrict__ Vtp,
                                                 unsigned short* __restrict__ Y) {
  // grid (NH, 16, B): h on the FAST axis so all 16 p-blocks of one (h,b) land
  // on the same XCD (flat%8 = h%8) and share the K/V panels in that XCD's L2.
  int p = blockIdx.y, h = blockIdx.x, b = blockIdx.z;
  if (b == 1) p = 15 - p;  // complementary pairing across the two dispatch halves
  int tid = threadIdx.x;
  int w = tid >> 6, l = tid & 63, lo = l & 15, hi = l >> 4;
  int kh = h >> 2;
  int qtA = p, qtB = 31 - p;
  int ntB = qtB + 1;                // >= 17
  int st = w >> 2, wq = w & 3;      // st: 0 = state B (waves 0-3), 1 = state A (waves 4-7)
  int qt = st ? qtA : qtB;
  int q0 = qt * 64 + wq * 16;
  int swz = 8 * (lo & 7);

  __shared__ __align__(16) unsigned short Ks[3][4096];
  __shared__ __align__(16) unsigned short Vs[3][4096];
  __shared__ __align__(16) unsigned short Ps[8192];  // 1024 shorts per wave
  unsigned short* PsW = &Ps[w * 1024];

  const unsigned short* Qb = Q + ((size_t)(b * NH_ + h) * T_) * 64;
  const unsigned short* Kb = Kp + ((size_t)(b * NKV_ + kh) * T_) * 64;
  const unsigned short* Vb = Vtp + ((size_t)(b * NH_ + h) * 64) * T_;

  bf16x8 q_0 = *(const bf16x8*)(Qb + (size_t)(q0 + lo) * 64 + hi * 8);
  bf16x8 q_1 = *(const bf16x8*)(Qb + (size_t)(q0 + lo) * 64 + 32 + hi * 8);

  f32x4 y[4];
#pragma unroll
  for (int nf = 0; nf < 4; ++nf) y[nf] = (f32x4){0.f, 0.f, 0.f, 0.f};
  float m = -INFINITY, lsum = 0.f;

  stage_kv8(Kb, Vb, 0, w, l, Ks[0], Vs[0]);
  stage_kv8(Kb, Vb, 64, w, l, Ks[1], Vs[1]);
  int cur = 0, wbuf = 2;

  for (int kt = 0; kt < ntB; ++kt) {
    if (kt + 1 < ntB) PIPE_BARRIER(2) else PIPE_BARRIER(0);
    if (kt + 2 < ntB) stage_kv8(Kb, Vb, (kt + 2) * 64, w, l, Ks[wbuf], Vs[wbuf]);

    if (kt <= qt) {
      int kv0 = kt * 64;
      const unsigned short* KsC = Ks[cur];
      const unsigned short* VsC = Vs[cur];

      // S^T = mfma(K, Q): D[key][q], q = lo, key = kv0 + nt*16 + hi*4 + r
      f32x4 s[4];
      __builtin_amdgcn_s_setprio(1);
#pragma unroll
      for (int nt = 0; nt < 4; ++nt) {
        int rrow = (nt * 16 + lo) * 64;
        int c0 = (hi * 8) ^ swz;
        bf16x8 kf0 = *(const bf16x8*)&KsC[rrow + c0];
        bf16x8 kf1 = *(const bf16x8*)&KsC[rrow + (c0 ^ 32)];
        f32x4 a = (f32x4){0.f, 0.f, 0.f, 0.f};
        a = __builtin_amdgcn_mfma_f32_16x16x32_bf16(kf0, q_0, a, 0, 0, 0);
        a = __builtin_amdgcn_mfma_f32_16x16x32_bf16(kf1, q_1, a, 0, 0, 0);
        s[nt] = a;
      }
      __builtin_amdgcn_s_setprio(0);

      if (kt == qt) {  // diagonal tile: causal mask
#pragma unroll
        for (int nt = 0; nt < 4; ++nt)
#pragma unroll
          for (int r = 0; r < 4; ++r)
            if (kv0 + nt * 16 + hi * 4 + r > q0 + lo) s[nt][r] = -1e30f;
      }

      softmax_state(s, m, lsum, y, PsW, lo, hi, swz);

      // PV: y[q][d] += P[q][k] * V[k][d]
      __builtin_amdgcn_s_setprio(1);
#pragma unroll
      for (int kc = 0; kc < 2; ++kc) {
        int pcol = (kc * 32 + hi * 8) ^ swz;
        bf16x8 pa = *(const bf16x8*)&PsW[lo * 64 + pcol];
#pragma unroll
        for (int nf = 0; nf < 4; ++nf) {
          bf16x8 vf = *(const bf16x8*)&VsC[(nf * 16 + lo) * 64 + pcol];
          y[nf] = __builtin_amdgcn_mfma_f32_16x16x32_bf16(pa, vf, y[nf], 0, 0, 0);
        }
      }
      __builtin_amdgcn_s_setprio(0);
    }

    cur = (cur == 2) ? 0 : cur + 1;
    wbuf = (wbuf == 2) ? 0 : wbuf + 1;
  }

  // epilogue: reduce per-lane partial sums, divide, store PRE-SWIZZLED y for proj
  lsum += __shfl_xor(lsum, 16);
  lsum += __shfl_xor(lsum, 32);
  float inv = frcp(lsum);
#pragma unroll
  for (int r = 0; r < 4; ++r) {
    float iv = __shfl(inv, hi * 4 + r);
    int t = q0 + hi * 4 + r;
    int sw = 8 * (t & 7);
    __bf16* yp = (__bf16*)(Y + ((size_t)(b * T_ + t)) * D_ + h * 64);
#pragma unroll
    for (int nf = 0; nf < 4; ++nf)
      yp[(nf * 16 + lo) ^ sw] = (__bf16)(y[nf][r] * iv);
  }
}

extern "C" void kernel_launch(void* const* d_in, const int* in_sizes, int n_in,
                              void* d_out, int out_size, void* d_ws, size_t ws_size,
                              hipStream_t stream) {
  const float* x     = (const float*)d_in[0];
  const float* cosT  = (const float*)d_in[1];
  const float* sinT  = (const float*)d_in[2];
  const float* v0    = (const float*)d_in[3];
  const float* Wqkv  = (const float*)d_in[4];
  const float* Wproj = (const float*)d_in[5];
  const float* vrl   = (const float*)d_in[6];
  const float* qks   = (const float*)d_in[7];
  float* out = (float*)d_out;

  char* ws = (char*)d_ws;
  unsigned short* xb     = (unsigned short*)ws;                   //  8388608 B (pre-swizzled)
  unsigned short* wqkvb  = (unsigned short*)(ws + 8388608);       //  3145728 B (pre-swizzled)
  unsigned short* wprojb = (unsigned short*)(ws + 11534336);      //  2097152 B (pre-swizzled)
  unsigned short* qb     = (unsigned short*)(ws + 13631488);      //  8388608 B
  unsigned short* kb     = (unsigned short*)(ws + 22020096);      //  2097152 B (d-swizzled)
  unsigned short* vb     = (unsigned short*)(ws + 24117248);      //  8388608 B (V^T swizzled)
  unsigned short* yb     = (unsigned short*)(ws + 32505856);      //  8388608 B (pre-swizzled)

  k_convert_all<<<3328, 256, 0, stream>>>(x, Wqkv, Wproj, xb, wqkvb, wprojb);

  k_gemm_qkv<<<dim3(12, 32), 256, 0, stream>>>(xb, wqkvb, cosT, sinT, v0, vrl, qks, qb, kb, vb);

  k_attn<<<dim3(NH_, 16, B_), 512, 0, stream>>>(qb, kb, vb, yb);

  k_gemm_proj<<<dim3(8, 48), 256, 0, stream>>>(yb, wprojb, v0, out, out + 4194304);
}